// Round 11
// baseline (44.874 us; speedup 1.0000x reference)
//
#include <hip/hip_runtime.h>
#include <float.h>

#define NB 64
#define NS 512
#define NH 768
#define NL 32
#define NK 8
#define NCH 32          // chunks per sample (16 rows each)
#define NCHB (NB*NS/16) // 2048 chunk blocks in kA

#define OFF_START 0
#define OFF_END   (NB*NS)
#define OFF_SPANS (2*NB*NS)
#define OFF_NSP   (2*NB*NS + NB*NL)
#define OFF_SOH   (2*NB*NS + NB*NL + NB*9)
#define OFF_EOH   (3*NB*NS + NB*NL + NB*9)
#define OFF_LAB   (4*NB*NS + NB*NL + NB*9)

// ---------------- Kernel A: start/end logits + 16-row chunk partial sums,
// plus (extra 64 blocks, hidden under the HBM-bound ones) the seq-head GEMV.
__global__ __launch_bounds__(512) void kA(const float* __restrict__ T,
                                          const float* __restrict__ Ws,
                                          const float* __restrict__ We,
                                          const float* __restrict__ bs,
                                          const float* __restrict__ be,
                                          const float* __restrict__ seq_rep,
                                          const float* __restrict__ W_nspans,
                                          const float* __restrict__ b_nspans,
                                          const float* __restrict__ W_span,
                                          const float* __restrict__ b_span,
                                          float* __restrict__ out,
                                          float4* __restrict__ wsC,
                                          float* __restrict__ wsF) {
    int j   = blockIdx.x;
    int tid = threadIdx.x;

    if (j >= NCHB) {   // ---- seq-head block: 41-output GEMV for sample b ----
        int b = j - NCHB;
        __shared__ float part[6][41];
        if (tid < 246) {
            int t = tid, g = t / 41, l = t % 41;
            int h0 = g * 128;
            const float* sr = seq_rep + b * NH;
            float acc = 0.f;
            if (l < 32) {
                for (int h = h0; h < h0 + 128; ++h) acc += sr[h] * W_span[h * NL + l];
            } else {
                int jj = l - 32;
                for (int h = h0; h < h0 + 128; ++h) acc += sr[h] * W_nspans[h * 9 + jj];
            }
            part[g][l] = acc;
        }
        __syncthreads();
        if (tid < 41) {
            float a = 0.f;
#pragma unroll
            for (int g = 0; g < 6; ++g) a += part[g][tid];
            if (tid < 32) wsF[b * 32 + tid] = a + b_span[tid];
            else          out[OFF_NSP + b * 9 + (tid - 32)] = a + b_nspans[tid - 32];
        }
        return;
    }

    int wave = tid >> 6, lane = tid & 63;
    int row  = j * 16 + wave * 2;          // (b*512+s)

    if (j < 4)           out[OFF_SPANS + j * 512 + tid] = -FLT_MAX;
    else if (j < 8)      out[OFF_LAB + (j - 4) * 512 + tid] = 0.f;

    __shared__ float4 smc[8][192];

    const float4* p0  = (const float4*)(T + (size_t)row * NH);
    const float4* p1  = (const float4*)(T + (size_t)(row + 1) * NH);
    const float4* w4s = (const float4*)Ws;
    const float4* w4e = (const float4*)We;
    float as0 = 0.f, ae0 = 0.f, as1 = 0.f, ae1 = 0.f;
    float4 sum[3];
#pragma unroll
    for (int c = 0; c < 3; ++c) {
        float4 t0 = p0[lane + c * 64];
        float4 t1 = p1[lane + c * 64];
        float4 a  = w4s[lane + c * 64];
        float4 bb = w4e[lane + c * 64];
        as0 += t0.x * a.x + t0.y * a.y + t0.z * a.z + t0.w * a.w;
        ae0 += t0.x * bb.x + t0.y * bb.y + t0.z * bb.z + t0.w * bb.w;
        as1 += t1.x * a.x + t1.y * a.y + t1.z * a.z + t1.w * a.w;
        ae1 += t1.x * bb.x + t1.y * bb.y + t1.z * bb.z + t1.w * bb.w;
        sum[c].x = t0.x + t1.x; sum[c].y = t0.y + t1.y;
        sum[c].z = t0.z + t1.z; sum[c].w = t0.w + t1.w;
    }
#pragma unroll
    for (int off = 32; off > 0; off >>= 1) {
        as0 += __shfl_down(as0, off);
        ae0 += __shfl_down(ae0, off);
        as1 += __shfl_down(as1, off);
        ae1 += __shfl_down(ae1, off);
    }
    if (lane == 0) {
        out[OFF_START + row]     = as0 + bs[0];
        out[OFF_START + row + 1] = as1 + bs[0];
        out[OFF_END   + row]     = ae0 + be[0];
        out[OFF_END   + row + 1] = ae1 + be[0];
    }

    smc[wave][lane]       = sum[0];
    smc[wave][lane + 64]  = sum[1];
    smc[wave][lane + 128] = sum[2];
    __syncthreads();
    if (tid < 192) {
        float4 v = make_float4(0.f, 0.f, 0.f, 0.f);
#pragma unroll
        for (int w = 0; w < 8; ++w) {
            float4 u = smc[w][tid];
            v.x += u.x; v.y += u.y; v.z += u.z; v.w += u.w;
        }
        wsC[(size_t)j * 192 + tid] = v;   // 16-row chunk partial (768 floats)
    }
}

// Register-resident wave top-8 over 512 values (tie -> lower index, matching
// stable lax.top_k). Lane holds values at indices {lane, lane+64, ..., lane+448}.
__device__ __forceinline__ void waveTop8(const float* __restrict__ g, int lane,
                                         int* __restrict__ dst) {
    float v0 = g[lane],       v1 = g[lane + 64],  v2 = g[lane + 128], v3 = g[lane + 192];
    float v4 = g[lane + 256], v5 = g[lane + 320], v6 = g[lane + 384], v7 = g[lane + 448];
#pragma unroll
    for (int r = 0; r < 8; ++r) {
        float bv = v0; int bi = lane;
        if (v1 > bv) { bv = v1; bi = lane + 64; }
        if (v2 > bv) { bv = v2; bi = lane + 128; }
        if (v3 > bv) { bv = v3; bi = lane + 192; }
        if (v4 > bv) { bv = v4; bi = lane + 256; }
        if (v5 > bv) { bv = v5; bi = lane + 320; }
        if (v6 > bv) { bv = v6; bi = lane + 384; }
        if (v7 > bv) { bv = v7; bi = lane + 448; }
#pragma unroll
        for (int off = 32; off > 0; off >>= 1) {
            float ov = __shfl_xor(bv, off);
            int   oi = __shfl_xor(bi, off);
            if (ov > bv || (ov == bv && oi < bi)) { bv = ov; bi = oi; }
        }
        if (lane == 0) dst[r] = bi;
        if      (bi == lane)       v0 = -FLT_MAX;
        else if (bi == lane + 64)  v1 = -FLT_MAX;
        else if (bi == lane + 128) v2 = -FLT_MAX;
        else if (bi == lane + 192) v3 = -FLT_MAX;
        else if (bi == lane + 256) v4 = -FLT_MAX;
        else if (bi == lane + 320) v5 = -FLT_MAX;
        else if (bi == lane + 384) v6 = -FLT_MAX;
        else if (bi == lane + 448) v7 = -FLT_MAX;
    }
}

__device__ __forceinline__ void atomicMaxFloat(float* addr, float val) {
    unsigned int* ua = (unsigned int*)addr;
    unsigned int old = __float_as_uint(*addr);
    while (__uint_as_float(old) < val) {
        unsigned int assumed = old;
        old = atomicCAS(ua, assumed, __float_as_uint(val));
        if (old == assumed) break;
    }
}

#define ACC3(P) do { \
    const float4* _p = (P); \
    float4 _x0 = _p[0], _x1 = _p[64], _x2 = _p[128]; \
    a0.x += _x0.x; a0.y += _x0.y; a0.z += _x0.z; a0.w += _x0.w; \
    a1.x += _x1.x; a1.y += _x1.y; a1.z += _x1.z; a1.w += _x1.w; \
    a2.x += _x2.x; a2.y += _x2.y; a2.z += _x2.z; a2.w += _x2.w; \
} while (0)

// ---------------- Kernel BCD: 9 blocks/sample. Phase 1 = topk only (GEMV was
// precomputed in kA); merge; control block emits control outputs; span blocks
// compose spans/labels fence-free (atomicMax / benign store).
__global__ __launch_bounds__(512) void kBCD(const float* __restrict__ T,
                                            const float4* __restrict__ wsC,
                                            const float* __restrict__ wsF,
                                            const float* __restrict__ W_span,
                                            const float* __restrict__ b_span,
                                            float* __restrict__ out) {
    int k = blockIdx.x, b = blockIdx.y;
    int tid = threadIdx.x, wave = tid >> 6, lane = tid & 63;

    __shared__ int    topS[NK], topE[NK];
    __shared__ float  fl[NL], nsp[9];
    __shared__ int    saS[NK], eaS[NK];
    __shared__ int    meta[3];              // ns, cnt, af
    __shared__ float4 sm4[8][192];
    __shared__ float  vec[NH];
    __shared__ float  pl[8][32];

    // ---- Phase 1: topk (waves 0-1) || tiny loads of precomputed heads ----
    if (tid < 64) {
        waveTop8(out + OFF_START + b * NS, tid, topS);
    } else if (tid < 128) {
        waveTop8(out + OFF_END + b * NS, tid - 64, topE);
    } else if (tid >= 128 && tid < 137) {
        nsp[tid - 128] = out[OFF_NSP + b * 9 + (tid - 128)];
    } else if (k == NK && tid >= 160 && tid < 192) {
        fl[tid - 160] = wsF[b * 32 + (tid - 160)];
    }
    __syncthreads();

    // ---- Merge (thread 0, redundant per block) ----
    if (tid == 0) {
        int ns = 0; float bv = nsp[0];
        for (int j = 1; j < 9; ++j) if (nsp[j] > bv) { bv = nsp[j]; ns = j; }

        int ss[NK], es[NK];
        for (int i = 0; i < NK; ++i) {
            ss[i] = (i < ns) ? topS[i] : NS;
            es[i] = (i < ns) ? topE[i] : NS;
        }
        for (int i = 1; i < NK; ++i) {
            int v = ss[i], j2 = i - 1;
            while (j2 >= 0 && ss[j2] > v) { ss[j2 + 1] = ss[j2]; --j2; }
            ss[j2 + 1] = v;
        }
        for (int i = 1; i < NK; ++i) {
            int v = es[i], j2 = i - 1;
            while (j2 >= 0 && es[j2] > v) { es[j2 + 1] = es[j2]; --j2; }
            es[j2 + 1] = v;
        }
        int sa[NK], ea[NK];
        for (int i = 0; i < NK; ++i) { sa[i] = 0; ea[i] = 0; }
        int si = 0, ei = 0, nrem = ns, last = 0, cnt = 0;
        while (nrem > 0 && si < ns && ei < ns) {
            int s = ss[si], e = es[ei];
            bool take = (e > s) && (s >= last);
            if (take) { sa[cnt] = s; ea[cnt] = e; last = e; ++cnt; --nrem; }
            if (e > s) ++si;
            if (take || e <= s) ++ei;
        }
        int af = 0;
        if (k == NK) {                      // only control block has fl
            float fv = fl[0];
            for (int l = 1; l < NL; ++l) if (fl[l] > fv) { fv = fl[l]; af = l; }
        }
        meta[0] = ns; meta[1] = cnt; meta[2] = af;
        for (int i = 0; i < NK; ++i) { saS[i] = sa[i]; eaS[i] = ea[i]; }
    }
    __syncthreads();

    int ns = meta[0], cnt = meta[1], af = meta[2];
    bool multi = ns > 1;

    if (k == NK) {   // control block
        if (!multi) {
            if (tid < NL) {
                out[OFF_SPANS + b * NL + tid] = fl[tid];
                out[OFF_LAB   + b * NL + tid] = (tid == af) ? 1.f : 0.f;
            }
            out[OFF_SOH + b * NS + tid] = (tid == topS[0]) ? 1.f : 0.f;
            out[OFF_EOH + b * NS + tid] = (tid == topE[0]) ? 1.f : 0.f;
        } else {
            float svv = 0.f, evv = 0.f;
            for (int kk = 0; kk < cnt; ++kk) {
                if (saS[kk] == tid) svv = 1.f;
                if (eaS[kk] == tid) evv = 1.f;
            }
            out[OFF_SOH + b * NS + tid] = svv;
            out[OFF_EOH + b * NS + tid] = evv;
            if (cnt == 0 && tid < NL) {
                out[OFF_SPANS + b * NL + tid] = 0.f;   // overwrite -FLT_MAX init
            }
        }
        return;
    }

    if (!multi || k >= cnt) return;   // block-uniform exit

    // ---- Phase 2: span k sum = 16-row chunk partials + edge rows ----
    int s = saS[k], e = eaS[k];
    float4 a0 = make_float4(0.f, 0.f, 0.f, 0.f), a1 = a0, a2 = a0;
    const float4* Tb = (const float4*)(T + (size_t)b * NS * NH);
    const float4* Cb = wsC + (size_t)b * NCH * 192;

    int c0 = (s + 15) >> 4, c1 = e >> 4;
    if (c0 < c1) {
        for (int c = c0 + wave; c < c1; c += 8) ACC3(Cb + (size_t)c * 192 + lane);
        for (int r = s + wave; r < (c0 << 4); r += 8) ACC3(Tb + (size_t)r * 192 + lane);
        for (int r = (c1 << 4) + wave; r < e; r += 8) ACC3(Tb + (size_t)r * 192 + lane);
    } else {
        for (int r = s + wave; r < e; r += 8) ACC3(Tb + (size_t)r * 192 + lane);
    }

    sm4[wave][lane]       = a0;
    sm4[wave][lane + 64]  = a1;
    sm4[wave][lane + 128] = a2;
    __syncthreads();

    if (tid < 192) {
        float inv = 1.f / (float)(e - s);
        float4 v = make_float4(0.f, 0.f, 0.f, 0.f);
#pragma unroll
        for (int w = 0; w < 8; ++w) {
            float4 u = sm4[w][tid];
            v.x += u.x; v.y += u.y; v.z += u.z; v.w += u.w;
        }
        v.x *= inv; v.y *= inv; v.z *= inv; v.w *= inv;
        ((float4*)vec)[tid] = v;
    }
    __syncthreads();

    if (tid < 256) {
        int g = tid >> 5, l = tid & 31;
        float acc = 0.f;
        int h0 = g * 96;
        for (int h = h0; h < h0 + 96; ++h) acc += vec[h] * W_span[h * NL + l];
        pl[g][l] = acc;
    }
    __syncthreads();
    if (tid < 32) {
        float a = b_span[tid];
#pragma unroll
        for (int gg = 0; gg < 8; ++gg) a += pl[gg][tid];
        atomicMaxFloat(&out[OFF_SPANS + b * NL + tid], a);   // fence-free max-reduce
        float bv = a; int bi = tid;
#pragma unroll
        for (int off = 16; off > 0; off >>= 1) {
            float ov = __shfl_xor(bv, off, 32);
            int   oi = __shfl_xor(bi, off, 32);
            if (ov > bv || (ov == bv && oi < bi)) { bv = ov; bi = oi; }
        }
        if (tid == 0) out[OFF_LAB + b * NL + bi] = 1.f;   // benign racing store of 1.0
    }
}

extern "C" void kernel_launch(void* const* d_in, const int* in_sizes, int n_in,
                              void* d_out, int out_size, void* d_ws, size_t ws_size,
                              hipStream_t stream) {
    const float* tokens   = (const float*)d_in[0];
    const float* seq_rep  = (const float*)d_in[1];
    const float* W_start  = (const float*)d_in[2];
    const float* b_start  = (const float*)d_in[3];
    const float* W_end    = (const float*)d_in[4];
    const float* b_end    = (const float*)d_in[5];
    const float* W_nspans = (const float*)d_in[6];
    const float* b_nspans = (const float*)d_in[7];
    const float* W_span   = (const float*)d_in[8];
    const float* b_span   = (const float*)d_in[9];
    float* out = (float*)d_out;

    size_t wsCbytes = (size_t)NB * NCH * NH * sizeof(float);   // 6.3 MB chunk partials
    float4* wsC = (float4*)d_ws;
    float*  wsF = (float*)((char*)d_ws + wsCbytes);            // 64*32 floats

    kA<<<NCHB + NB, 512, 0, stream>>>(tokens, W_start, W_end, b_start, b_end,
                                      seq_rep, W_nspans, b_nspans, W_span, b_span,
                                      out, wsC, wsF);
    kBCD<<<dim3(NK + 1, NB), 512, 0, stream>>>(tokens, wsC, wsF, W_span, b_span, out);
}

// Round 12
// 41.893 us; speedup vs baseline: 1.0712x; 1.0712x over previous
//
#include <hip/hip_runtime.h>
#include <float.h>

#define NB 64
#define NS 512
#define NH 768
#define NL 32
#define NK 8
#define NCH 32          // chunks per sample (16 rows each)

#define OFF_START 0
#define OFF_END   (NB*NS)
#define OFF_SPANS (2*NB*NS)
#define OFF_NSP   (2*NB*NS + NB*NL)
#define OFF_SOH   (2*NB*NS + NB*NL + NB*9)
#define OFF_EOH   (3*NB*NS + NB*NL + NB*9)
#define OFF_LAB   (4*NB*NS + NB*NL + NB*9)

// ---------------- Kernel A: start/end logits + 16-row chunk partial sums -----
__global__ __launch_bounds__(512) void kA(const float* __restrict__ T,
                                          const float* __restrict__ Ws,
                                          const float* __restrict__ We,
                                          const float* __restrict__ bs,
                                          const float* __restrict__ be,
                                          float* __restrict__ out,
                                          float4* __restrict__ wsC) {
    int j    = blockIdx.x;                 // global chunk id (b*32 + c)
    int tid  = threadIdx.x;
    int wave = tid >> 6, lane = tid & 63;
    int row  = j * 16 + wave * 2;          // (b*512+s)

    if (j < 4)           out[OFF_SPANS + j * 512 + tid] = -FLT_MAX;
    else if (j < 8)      out[OFF_LAB + (j - 4) * 512 + tid] = 0.f;

    __shared__ float4 smc[8][192];

    const float4* p0  = (const float4*)(T + (size_t)row * NH);
    const float4* p1  = (const float4*)(T + (size_t)(row + 1) * NH);
    const float4* w4s = (const float4*)Ws;
    const float4* w4e = (const float4*)We;
    float as0 = 0.f, ae0 = 0.f, as1 = 0.f, ae1 = 0.f;
    float4 sum[3];
#pragma unroll
    for (int c = 0; c < 3; ++c) {
        float4 t0 = p0[lane + c * 64];
        float4 t1 = p1[lane + c * 64];
        float4 a  = w4s[lane + c * 64];
        float4 bb = w4e[lane + c * 64];
        as0 += t0.x * a.x + t0.y * a.y + t0.z * a.z + t0.w * a.w;
        ae0 += t0.x * bb.x + t0.y * bb.y + t0.z * bb.z + t0.w * bb.w;
        as1 += t1.x * a.x + t1.y * a.y + t1.z * a.z + t1.w * a.w;
        ae1 += t1.x * bb.x + t1.y * bb.y + t1.z * bb.z + t1.w * bb.w;
        sum[c].x = t0.x + t1.x; sum[c].y = t0.y + t1.y;
        sum[c].z = t0.z + t1.z; sum[c].w = t0.w + t1.w;
    }
#pragma unroll
    for (int off = 32; off > 0; off >>= 1) {
        as0 += __shfl_down(as0, off);
        ae0 += __shfl_down(ae0, off);
        as1 += __shfl_down(as1, off);
        ae1 += __shfl_down(ae1, off);
    }
    if (lane == 0) {
        out[OFF_START + row]     = as0 + bs[0];
        out[OFF_START + row + 1] = as1 + bs[0];
        out[OFF_END   + row]     = ae0 + be[0];
        out[OFF_END   + row + 1] = ae1 + be[0];
    }

    smc[wave][lane]       = sum[0];
    smc[wave][lane + 64]  = sum[1];
    smc[wave][lane + 128] = sum[2];
    __syncthreads();
    if (tid < 192) {
        float4 v = make_float4(0.f, 0.f, 0.f, 0.f);
#pragma unroll
        for (int w = 0; w < 8; ++w) {
            float4 u = smc[w][tid];
            v.x += u.x; v.y += u.y; v.z += u.z; v.w += u.w;
        }
        wsC[(size_t)j * 192 + tid] = v;   // 16-row chunk partial (768 floats)
    }
}

// Register-resident wave top-8 over 512 values (tie -> lower index, matching
// stable lax.top_k). Lane holds values at indices {lane, lane+64, ..., lane+448}.
__device__ __forceinline__ void waveTop8(const float* __restrict__ g, int lane,
                                         int* __restrict__ dst) {
    float v0 = g[lane],       v1 = g[lane + 64],  v2 = g[lane + 128], v3 = g[lane + 192];
    float v4 = g[lane + 256], v5 = g[lane + 320], v6 = g[lane + 384], v7 = g[lane + 448];
#pragma unroll
    for (int r = 0; r < 8; ++r) {
        float bv = v0; int bi = lane;
        if (v1 > bv) { bv = v1; bi = lane + 64; }
        if (v2 > bv) { bv = v2; bi = lane + 128; }
        if (v3 > bv) { bv = v3; bi = lane + 192; }
        if (v4 > bv) { bv = v4; bi = lane + 256; }
        if (v5 > bv) { bv = v5; bi = lane + 320; }
        if (v6 > bv) { bv = v6; bi = lane + 384; }
        if (v7 > bv) { bv = v7; bi = lane + 448; }
#pragma unroll
        for (int off = 32; off > 0; off >>= 1) {
            float ov = __shfl_xor(bv, off);
            int   oi = __shfl_xor(bi, off);
            if (ov > bv || (ov == bv && oi < bi)) { bv = ov; bi = oi; }
        }
        if (lane == 0) dst[r] = bi;
        if      (bi == lane)       v0 = -FLT_MAX;
        else if (bi == lane + 64)  v1 = -FLT_MAX;
        else if (bi == lane + 128) v2 = -FLT_MAX;
        else if (bi == lane + 192) v3 = -FLT_MAX;
        else if (bi == lane + 256) v4 = -FLT_MAX;
        else if (bi == lane + 320) v5 = -FLT_MAX;
        else if (bi == lane + 384) v6 = -FLT_MAX;
        else if (bi == lane + 448) v7 = -FLT_MAX;
    }
}

__device__ __forceinline__ void atomicMaxFloat(float* addr, float val) {
    unsigned int* ua = (unsigned int*)addr;
    unsigned int old = __float_as_uint(*addr);
    while (__uint_as_float(old) < val) {
        unsigned int assumed = old;
        old = atomicCAS(ua, assumed, __float_as_uint(val));
        if (old == assumed) break;
    }
}

#define ACC3(P) do { \
    const float4* _p = (P); \
    float4 _x0 = _p[0], _x1 = _p[64], _x2 = _p[128]; \
    a0.x += _x0.x; a0.y += _x0.y; a0.z += _x0.z; a0.w += _x0.w; \
    a1.x += _x1.x; a1.y += _x1.y; a1.z += _x1.z; a1.w += _x1.w; \
    a2.x += _x2.x; a2.y += _x2.y; a2.z += _x2.z; a2.w += _x2.w; \
} while (0)

// ---------------- Kernel BCD: 9 blocks/sample, redundant heads+topk+merge.
// Control block (k==8): nsp, one-hots, single/cnt==0 outputs. Span blocks:
// span logits -> fence-free composition (atomicMax spans / benign store labels).
// Both GEMVs 4-way unrolled for load pipelining (latency, not bandwidth, bound).
__global__ __launch_bounds__(512) void kBCD(const float* __restrict__ T,
                                            const float4* __restrict__ wsC,
                                            const float* __restrict__ seq_rep,
                                            const float* __restrict__ W_nspans,
                                            const float* __restrict__ b_nspans,
                                            const float* __restrict__ W_span,
                                            const float* __restrict__ b_span,
                                            float* __restrict__ out) {
    int k = blockIdx.x, b = blockIdx.y;
    int tid = threadIdx.x, wave = tid >> 6, lane = tid & 63;

    __shared__ int    topS[NK], topE[NK];
    __shared__ float  part[6][41];
    __shared__ float  fl[NL], nsp[9];
    __shared__ int    saS[NK], eaS[NK];
    __shared__ int    meta[3];              // ns, cnt, af
    __shared__ float4 sm4[8][192];
    __shared__ float  vec[NH];
    __shared__ float  pl[8][32];

    // ---- Phase 1 (all blocks, parallel): topk || 41-out GEMV (pipelined) ----
    if (tid < 64) {
        waveTop8(out + OFF_START + b * NS, tid, topS);
    } else if (tid < 128) {
        waveTop8(out + OFF_END + b * NS, tid - 64, topE);
    } else if (tid < 128 + 246) {
        int t = tid - 128, g = t / 41, l = t % 41;
        int h0 = g * 128;
        const float* sr = seq_rep + b * NH;
        float ac0 = 0.f, ac1 = 0.f, ac2 = 0.f, ac3 = 0.f;
        if (l < 32) {
            const float* Wp = W_span + l;
#pragma unroll
            for (int h = h0; h < h0 + 128; h += 4) {
                ac0 += sr[h]     * Wp[h * NL];
                ac1 += sr[h + 1] * Wp[(h + 1) * NL];
                ac2 += sr[h + 2] * Wp[(h + 2) * NL];
                ac3 += sr[h + 3] * Wp[(h + 3) * NL];
            }
        } else {
            const float* Wp = W_nspans + (l - 32);
#pragma unroll
            for (int h = h0; h < h0 + 128; h += 4) {
                ac0 += sr[h]     * Wp[h * 9];
                ac1 += sr[h + 1] * Wp[(h + 1) * 9];
                ac2 += sr[h + 2] * Wp[(h + 2) * 9];
                ac3 += sr[h + 3] * Wp[(h + 3) * 9];
            }
        }
        part[g][l] = (ac0 + ac1) + (ac2 + ac3);
    }
    __syncthreads();
    if (tid < 41) {
        float a = 0.f;
#pragma unroll
        for (int g = 0; g < 6; ++g) a += part[g][tid];
        if (tid < 32) fl[tid] = a + b_span[tid];
        else          nsp[tid - 32] = a + b_nspans[tid - 32];
    }
    __syncthreads();

    // ---- Merge (thread 0, redundant per block) ----
    if (tid == 0) {
        int ns = 0; float bv = nsp[0];
        for (int j = 1; j < 9; ++j) if (nsp[j] > bv) { bv = nsp[j]; ns = j; }

        int ss[NK], es[NK];
        for (int i = 0; i < NK; ++i) {
            ss[i] = (i < ns) ? topS[i] : NS;
            es[i] = (i < ns) ? topE[i] : NS;
        }
        for (int i = 1; i < NK; ++i) {
            int v = ss[i], j2 = i - 1;
            while (j2 >= 0 && ss[j2] > v) { ss[j2 + 1] = ss[j2]; --j2; }
            ss[j2 + 1] = v;
        }
        for (int i = 1; i < NK; ++i) {
            int v = es[i], j2 = i - 1;
            while (j2 >= 0 && es[j2] > v) { es[j2 + 1] = es[j2]; --j2; }
            es[j2 + 1] = v;
        }
        int sa[NK], ea[NK];
        for (int i = 0; i < NK; ++i) { sa[i] = 0; ea[i] = 0; }
        int si = 0, ei = 0, nrem = ns, last = 0, cnt = 0;
        while (nrem > 0 && si < ns && ei < ns) {
            int s = ss[si], e = es[ei];
            bool take = (e > s) && (s >= last);
            if (take) { sa[cnt] = s; ea[cnt] = e; last = e; ++cnt; --nrem; }
            if (e > s) ++si;
            if (take || e <= s) ++ei;
        }
        int af = 0; float fv = fl[0];
        for (int l = 1; l < NL; ++l) if (fl[l] > fv) { fv = fl[l]; af = l; }

        meta[0] = ns; meta[1] = cnt; meta[2] = af;
        for (int i = 0; i < NK; ++i) { saS[i] = sa[i]; eaS[i] = ea[i]; }
    }
    __syncthreads();

    int ns = meta[0], cnt = meta[1], af = meta[2];
    bool multi = ns > 1;

    if (k == NK) {   // control block
        if (tid < 9) out[OFF_NSP + b * 9 + tid] = nsp[tid];
        if (!multi) {
            if (tid < NL) {
                out[OFF_SPANS + b * NL + tid] = fl[tid];
                out[OFF_LAB   + b * NL + tid] = (tid == af) ? 1.f : 0.f;
            }
            out[OFF_SOH + b * NS + tid] = (tid == topS[0]) ? 1.f : 0.f;
            out[OFF_EOH + b * NS + tid] = (tid == topE[0]) ? 1.f : 0.f;
        } else {
            float svv = 0.f, evv = 0.f;
            for (int kk = 0; kk < cnt; ++kk) {
                if (saS[kk] == tid) svv = 1.f;
                if (eaS[kk] == tid) evv = 1.f;
            }
            out[OFF_SOH + b * NS + tid] = svv;
            out[OFF_EOH + b * NS + tid] = evv;
            if (cnt == 0 && tid < NL) {
                out[OFF_SPANS + b * NL + tid] = 0.f;   // overwrite -FLT_MAX init
            }
        }
        return;
    }

    if (!multi || k >= cnt) return;   // block-uniform exit

    // ---- Phase 2: span k sum = 16-row chunk partials + edge rows ----
    int s = saS[k], e = eaS[k];
    float4 a0 = make_float4(0.f, 0.f, 0.f, 0.f), a1 = a0, a2 = a0;
    const float4* Tb = (const float4*)(T + (size_t)b * NS * NH);
    const float4* Cb = wsC + (size_t)b * NCH * 192;

    int c0 = (s + 15) >> 4, c1 = e >> 4;
    if (c0 < c1) {
        for (int c = c0 + wave; c < c1; c += 8) ACC3(Cb + (size_t)c * 192 + lane);
        for (int r = s + wave; r < (c0 << 4); r += 8) ACC3(Tb + (size_t)r * 192 + lane);
        for (int r = (c1 << 4) + wave; r < e; r += 8) ACC3(Tb + (size_t)r * 192 + lane);
    } else {
        for (int r = s + wave; r < e; r += 8) ACC3(Tb + (size_t)r * 192 + lane);
    }

    sm4[wave][lane]       = a0;
    sm4[wave][lane + 64]  = a1;
    sm4[wave][lane + 128] = a2;
    __syncthreads();

    if (tid < 192) {
        float inv = 1.f / (float)(e - s);
        float4 v = make_float4(0.f, 0.f, 0.f, 0.f);
#pragma unroll
        for (int w = 0; w < 8; ++w) {
            float4 u = sm4[w][tid];
            v.x += u.x; v.y += u.y; v.z += u.z; v.w += u.w;
        }
        v.x *= inv; v.y *= inv; v.z *= inv; v.w *= inv;
        ((float4*)vec)[tid] = v;
    }
    __syncthreads();

    if (tid < 256) {
        int g = tid >> 5, l = tid & 31;
        int h0 = g * 96;
        const float* Wp = W_span + l;
        float ac0 = 0.f, ac1 = 0.f, ac2 = 0.f, ac3 = 0.f;
#pragma unroll
        for (int h = h0; h < h0 + 96; h += 4) {
            ac0 += vec[h]     * Wp[h * NL];
            ac1 += vec[h + 1] * Wp[(h + 1) * NL];
            ac2 += vec[h + 2] * Wp[(h + 2) * NL];
            ac3 += vec[h + 3] * Wp[(h + 3) * NL];
        }
        pl[g][l] = (ac0 + ac1) + (ac2 + ac3);
    }
    __syncthreads();
    if (tid < 32) {
        float a = b_span[tid];
#pragma unroll
        for (int gg = 0; gg < 8; ++gg) a += pl[gg][tid];
        atomicMaxFloat(&out[OFF_SPANS + b * NL + tid], a);   // fence-free max-reduce
        float bv = a; int bi = tid;
#pragma unroll
        for (int off = 16; off > 0; off >>= 1) {
            float ov = __shfl_xor(bv, off, 32);
            int   oi = __shfl_xor(bi, off, 32);
            if (ov > bv || (ov == bv && oi < bi)) { bv = ov; bi = oi; }
        }
        if (tid == 0) out[OFF_LAB + b * NL + bi] = 1.f;   // benign racing store of 1.0
    }
}

extern "C" void kernel_launch(void* const* d_in, const int* in_sizes, int n_in,
                              void* d_out, int out_size, void* d_ws, size_t ws_size,
                              hipStream_t stream) {
    const float* tokens   = (const float*)d_in[0];
    const float* seq_rep  = (const float*)d_in[1];
    const float* W_start  = (const float*)d_in[2];
    const float* b_start  = (const float*)d_in[3];
    const float* W_end    = (const float*)d_in[4];
    const float* b_end    = (const float*)d_in[5];
    const float* W_nspans = (const float*)d_in[6];
    const float* b_nspans = (const float*)d_in[7];
    const float* W_span   = (const float*)d_in[8];
    const float* b_span   = (const float*)d_in[9];
    float* out = (float*)d_out;

    float4* wsC = (float4*)d_ws;   // 6.3 MB chunk partials

    kA<<<(NB * NS) / 16, 512, 0, stream>>>(tokens, W_start, W_end, b_start, b_end, out, wsC);
    kBCD<<<dim3(NK + 1, NB), 512, 0, stream>>>(tokens, wsC, seq_rep, W_nspans, b_nspans,
                                               W_span, b_span, out);
}